// Round 13
// baseline (114.205 us; speedup 1.0000x reference)
//
#include <hip/hip_runtime.h>

#define Gc 8
#define Dc 32
#define Hc 128
#define Wc 160
#define HW (Hc * Wc)         // 20480
#define DHW (Dc * HW)        // 655360

// ---------------------------------------------------------------------------
// XCD-locality swizzle (T1). Assumes hardware round-robins consecutive
// workgroup ids across the 8 XCDs (HK chiplet-transform assumption; if the
// real mapping differs this is still a bijection -> correctness unaffected).
// Goal: XCD k owns one contiguous (b, 32-row h-range) slice end-to-end:
//   - agg blocks on XCD k read offsets/sim only for that slice (~3 MB < 4 MB L2)
//   - mlp blocks on XCD k WRITE exactly that slice's sim -> producer/consumer
//     L2-local, no cross-XCD L3 round-trip for sim.
// ---------------------------------------------------------------------------

// ---------------------------------------------------------------------------
// Kernel A: per-point MLP 8 -> 16 -> 8 -> 1 (BN folded into LDS weights).
// One thread = TWO w-points (float2). Straight-line body (no loops: rounds
// 1-5 proved loops invite pipelining -> 208+ VGPR or spill; caps 84/64/128
// all spilled). ~60 VGPR -> 8 waves/SIMD.
// Block swizzle: physical blk -> (xcd = blk&7, i = blk>>3); b = xcd/4,
// q = xcd&3, d = i/10, rg = i%10; logical = (b*32+d)*40 + q*10 + rg.
// Logical block covers pixels [logical*512, +512) = rows h in
// [q*32 + rg*3.2 ...) of plane (b,d)  ->  XCD (b*4+q) writes exactly the
// sim rows h in [q*32, q*32+32) of batch b, matching agg's read slice.
// ---------------------------------------------------------------------------
__global__ __launch_bounds__(256) void mlp_kernel(
    const float* __restrict__ x1,
    const float* __restrict__ w0, const float* __restrict__ s0, const float* __restrict__ b0,
    const float* __restrict__ w1, const float* __restrict__ s1, const float* __restrict__ b1,
    const float* __restrict__ wsim, const float* __restrict__ bsim,
    float* __restrict__ sim)
{
    __shared__ float smw[289];
    const int tid = threadIdx.x;
    for (int i = tid; i < 289; i += 256) {
        float v;
        if (i < 128)      v = w0[i] * s0[i >> 3];                 // w0f[o][g]
        else if (i < 144) v = b0[i - 128];
        else if (i < 272) v = w1[i - 144] * s1[(i - 144) >> 4];   // w1f[c][o]
        else if (i < 280) v = b1[i - 272];
        else if (i < 288) v = wsim[i - 280];
        else              v = bsim[0];
        smw[i] = v;
    }
    __syncthreads();
    const float* sw0 = smw;
    const float* sb0 = smw + 128;
    const float* sw1 = smw + 144;
    const float* sb1 = smw + 272;
    const float* sws = smw + 280;
    const float  sbs = smw[288];

    // bijective XCD-chunk swizzle (2560 = 8 * 320 blocks)
    const int xcd = blockIdx.x & 7;
    const int i   = blockIdx.x >> 3;          // 0..319
    const int dd  = i / 10;                   // 0..31
    const int rg  = i - dd * 10;              // 0..9
    const int logical = (((xcd >> 2) * 32 + dd) * 40) + (xcd & 3) * 10 + rg;

    const int t   = logical * 256 + tid;      // 0 .. 655359 (bijective)
    const int p   = t << 1;                   // base point over (b,d,h,w)
    const int b   = p / DHW;
    const int dhw = p - b * DHW;
    const float* xb = x1 + (size_t)b * (Gc * DHW) + dhw;

    float2 xv[Gc];
#pragma unroll
    for (int g = 0; g < Gc; ++g)
        xv[g] = *reinterpret_cast<const float2*>(xb + g * DHW);

    float2 acc1[8];
#pragma unroll
    for (int c = 0; c < 8; ++c) {
        const float bb = sb1[c];
        acc1[c].x = bb; acc1[c].y = bb;
    }

#pragma unroll
    for (int o = 0; o < 16; ++o) {
        float ax = sb0[o], ay = ax;
#pragma unroll
        for (int g = 0; g < Gc; ++g) {
            const float wv = sw0[o * Gc + g];
            ax = fmaf(wv, xv[g].x, ax);
            ay = fmaf(wv, xv[g].y, ay);
        }
        ax = fmaxf(ax, 0.f);
        ay = fmaxf(ay, 0.f);
#pragma unroll
        for (int c = 0; c < 8; ++c) {
            const float wv = sw1[c * 16 + o];
            acc1[c].x = fmaf(wv, ax, acc1[c].x);
            acc1[c].y = fmaf(wv, ay, acc1[c].y);
        }
    }

    float sx = sbs, sy = sbs;
#pragma unroll
    for (int c = 0; c < 8; ++c) {
        const float ws = sws[c];
        sx = fmaf(ws, fmaxf(acc1[c].x, 0.f), sx);
        sy = fmaf(ws, fmaxf(acc1[c].y, 0.f), sy);
    }

    float2 r; r.x = sx; r.y = sy;
    *reinterpret_cast<float2*>(sim + p) = r;
}

// ---------------------------------------------------------------------------
// Kernel B: 9-neighbor aggregation, d-innermost decode (round-12 win).
// Block swizzle: physical blk -> logical lb = (blk&7)*160 + (blk>>3)
// (bijective, 1280 = 8*160). XCD k gets logical blocks [160k, 160k+160)
// = hb-range [32k, 32k+32): offsets 368 KB + sim ~2.7 MB fit its 4 MB L2,
// and that sim slice was produced on the SAME XCD by mlp's swizzle.
// ---------------------------------------------------------------------------
__global__ __launch_bounds__(256) void agg_kernel(
    const float* __restrict__ sim, const float* __restrict__ offset,
    const float* __restrict__ weight, float* __restrict__ out)
{
    const int lb = (blockIdx.x & 7) * 160 + (blockIdx.x >> 3);
    const int l  = lb * 256 + threadIdx.x;          // 0 .. 327679 (bijective)
    const int q  = l % (Wc / 4);
    const int w4 = q * 4;
    int r = l / (Wc / 4);
    const int d  = r & 31;                          // d fastest after w4
    r >>= 5;
    const int h  = r % Hc;
    const int b  = r / Hc;                          // 0..1
    const int hw4 = h * Wc + w4;

    const float* offb = offset + (size_t)b * 18 * HW;
    float4 off4[18];
#pragma unroll
    for (int s = 0; s < 18; ++s)
        off4[s] = *reinterpret_cast<const float4*>(offb + s * HW + hw4);
    float4 wt4 = *reinterpret_cast<const float4*>(weight + (size_t)b * HW + hw4);
    wt4.x *= 0.5f; wt4.y *= 0.5f; wt4.z *= 0.5f; wt4.w *= 0.5f;

    int y1[3], y2[3];
#pragma unroll
    for (int iy = 0; iy < 3; ++iy) {
        int a1 = h + (iy - 1) * 2; y1[iy] = a1 < 0 ? -a1 : (a1 >= Hc ? 2 * Hc - 2 - a1 : a1);
        int a2 = h + (iy - 1) * 4; y2[iy] = a2 < 0 ? -a2 : (a2 >= Hc ? 2 * Hc - 2 - a2 : a2);
    }

    const float* sp = sim + (size_t)(b * Dc + d) * HW;
    float ax = 0.f, ay = 0.f, az = 0.f, aw = 0.f;

    if (w4 >= 4 && w4 <= Wc - 8) {
        // interior: wide taps 16B-aligned float4; narrow taps two 8B float2
#pragma unroll
        for (int s = 0; s < 9; ++s) {
            const int iy = s / 3, ix = s % 3;
            const float4 cw = *reinterpret_cast<const float4*>(
                sp + y2[iy] * Wc + w4 + (ix - 1) * 4);
            const float* np = sp + y1[iy] * Wc + w4 + (ix - 1) * 2;
            const float2 n0 = *reinterpret_cast<const float2*>(np);
            const float2 n1 = *reinterpret_cast<const float2*>(np + 2);
            const float4 ow = off4[s];
            const float4 on = off4[s + 9];
            ax = fmaf(on.x, n0.x, fmaf(ow.x, cw.x, ax));
            ay = fmaf(on.y, n0.y, fmaf(ow.y, cw.y, ay));
            az = fmaf(on.z, n1.x, fmaf(ow.z, cw.z, az));
            aw = fmaf(on.w, n1.y, fmaf(ow.w, cw.w, aw));
        }
    } else {
        // edge quad (w4==0 or w4==Wc-4): scalar gathers with x-reflect
        float acc[4] = {0.f, 0.f, 0.f, 0.f};
#pragma unroll
        for (int j = 0; j < 4; ++j) {
            const int w = w4 + j;
            float a = 0.f;
#pragma unroll
            for (int s = 0; s < 9; ++s) {
                const int iy = s / 3, ix = s % 3;
                int x1c = w + (ix - 1) * 2; x1c = x1c < 0 ? -x1c : (x1c >= Wc ? 2 * Wc - 2 - x1c : x1c);
                int x2c = w + (ix - 1) * 4; x2c = x2c < 0 ? -x2c : (x2c >= Wc ? 2 * Wc - 2 - x2c : x2c);
                const float on = j == 0 ? off4[s + 9].x : j == 1 ? off4[s + 9].y : j == 2 ? off4[s + 9].z : off4[s + 9].w;
                const float ow = j == 0 ? off4[s].x     : j == 1 ? off4[s].y     : j == 2 ? off4[s].z     : off4[s].w;
                a = fmaf(on, sp[y1[iy] * Wc + x1c], fmaf(ow, sp[y2[iy] * Wc + x2c], a));
            }
            acc[j] = a;
        }
        ax = acc[0]; ay = acc[1]; az = acc[2]; aw = acc[3];
    }

    float4 o4;
    o4.x = ax * wt4.x;
    o4.y = ay * wt4.y;
    o4.z = az * wt4.z;
    o4.w = aw * wt4.w;
    float* outb = out + (size_t)(b * Dc + d) * HW;
    *reinterpret_cast<float4*>(outb + hw4) = o4;
}

extern "C" void kernel_launch(void* const* d_in, const int* in_sizes, int n_in,
                              void* d_out, int out_size, void* d_ws, size_t ws_size,
                              hipStream_t stream)
{
    const float* x1     = (const float*)d_in[0];
    const float* offset = (const float*)d_in[1];
    const float* weight = (const float*)d_in[2];
    const float* w0     = (const float*)d_in[3];
    const float* s0     = (const float*)d_in[4];
    const float* b0     = (const float*)d_in[5];
    const float* w1     = (const float*)d_in[6];
    const float* s1     = (const float*)d_in[7];
    const float* b1     = (const float*)d_in[8];
    const float* wsim   = (const float*)d_in[9];
    const float* bsim   = (const float*)d_in[10];
    float* out = (float*)d_out;
    float* sim = (float*)d_ws;   // B*D*H*W floats = 5.25 MB scratch

    // 655360 point-pairs / 256 = 2560 blocks (exact)
    mlp_kernel<<<2560, 256, 0, stream>>>(x1, w0, s0, b0, w1, s1, b1, wsim, bsim, sim);
    // 327680 output-quads / 256 = 1280 blocks (exact)
    agg_kernel<<<1280, 256, 0, stream>>>(sim, offset, weight, out);
}